// Round 1
// baseline (476.209 us; speedup 1.0000x reference)
//
#include <hip/hip_runtime.h>

// Instant-NGP style multiresolution hash encoding, forward only.
// N=1048576 points, L=16 levels, F=2 features, T=2^19 table entries.
//
// Resolutions: floor(16 * (8^(1/15))^l) emulated against host float64 libm.
// Knife-edge levels l=5,10,15 resolve to 32/64/128 (exp rounds UP at the
// last bit: exp(u) mantissa fraction ...252.534 -> 253). If absmax ~O(1),
// the fallback hypothesis is 31/63/127.
__constant__ float c_res[16] = {
    16.f, 18.f, 21.f, 24.f, 27.f, 32.f, 36.f, 42.f,
    48.f, 55.f, 64.f, 73.f, 84.f, 97.f, 111.f, 128.f
};

#define TMASK 0x7FFFFu   // T = 2^19, Python-mod of int32 == two's-complement mask
#define PRIME1 2654435761u
#define PRIME2 805459861u

// One thread per (point, level): tid = p*16 + l.
// Output element [p][l*2+f] == out_f2[tid] -> coalesced float2 stores.
__global__ __launch_bounds__(256, 8)
void FeatureField_kernel(const float* __restrict__ x,
                         const float2* __restrict__ tab,
                         float2* __restrict__ out,
                         int total)
{
    int tid = blockIdx.x * 256 + threadIdx.x;
    if (tid >= total) return;
    int p = tid >> 4;
    int l = tid & 15;

    float r = c_res[l];
    float x0 = x[3 * p + 0];
    float x1 = x[3 * p + 1];
    float x2 = x[3 * p + 2];

    // Lone fp32 multiplies: bit-identical to numpy float32 x*res.
    float s0 = x0 * r, s1 = x1 * r, s2 = x2 * r;
    float f0 = floorf(s0), f1 = floorf(s1), f2 = floorf(s2);
    float d0 = s0 - f0, d1 = s1 - f1, d2 = s2 - f2;

    // Hash components: floor (A) and ceil (B) corners per dim, int32-wrap mul.
    unsigned A0 = (unsigned)(int)f0;                       // * prime 1
    unsigned B0 = (unsigned)(int)ceilf(s0);
    unsigned A1 = (unsigned)(int)f1 * PRIME1;
    unsigned B1 = (unsigned)(int)ceilf(s1) * PRIME1;
    unsigned A2 = (unsigned)(int)f2 * PRIME2;
    unsigned B2 = (unsigned)(int)ceilf(s2) * PRIME2;

    // Corner order matches reference OFFSETS:
    // 000,100,010,001,110,101,011,111
    unsigned h0 = (A0 ^ A1 ^ A2) & TMASK;
    unsigned h1 = (B0 ^ A1 ^ A2) & TMASK;
    unsigned h2 = (A0 ^ B1 ^ A2) & TMASK;
    unsigned h3 = (A0 ^ A1 ^ B2) & TMASK;
    unsigned h4 = (B0 ^ B1 ^ A2) & TMASK;
    unsigned h5 = (B0 ^ A1 ^ B2) & TMASK;
    unsigned h6 = (A0 ^ B1 ^ B2) & TMASK;
    unsigned h7 = (B0 ^ B1 ^ B2) & TMASK;

    // 8 independent gathers (global_load_dwordx2), all in flight together.
    float2 v0 = tab[h0];
    float2 v1 = tab[h1];
    float2 v2 = tab[h2];
    float2 v3 = tab[h3];
    float2 v4 = tab[h4];
    float2 v5 = tab[h5];
    float2 v6 = tab[h6];
    float2 v7 = tab[h7];

    float u0 = 1.f - d0, u1 = 1.f - d1, u2 = 1.f - d2;
    float w0 = u0 * u1 * u2;
    float w1 = d0 * u1 * u2;
    float w2 = u0 * d1 * u2;
    float w3 = u0 * u1 * d2;
    float w4 = d0 * d1 * u2;
    float w5 = d0 * u1 * d2;
    float w6 = u0 * d1 * d2;
    float w7 = d0 * d1 * d2;

    // Accumulate in corner order (matches reference reduction order; fp32
    // association differences are ~1e-7, far under the 1.98e-2 threshold).
    float ex = v0.x * w0;
    float ey = v0.y * w0;
    ex += v1.x * w1;  ey += v1.y * w1;
    ex += v2.x * w2;  ey += v2.y * w2;
    ex += v3.x * w3;  ey += v3.y * w3;
    ex += v4.x * w4;  ey += v4.y * w4;
    ex += v5.x * w5;  ey += v5.y * w5;
    ex += v6.x * w6;  ey += v6.y * w6;
    ex += v7.x * w7;  ey += v7.y * w7;

    float2 o; o.x = ex; o.y = ey;
    out[tid] = o;
}

extern "C" void kernel_launch(void* const* d_in, const int* in_sizes, int n_in,
                              void* d_out, int out_size, void* d_ws, size_t ws_size,
                              hipStream_t stream)
{
    const float*  x   = (const float*)d_in[0];     // [N,3] float32
    const float2* tab = (const float2*)d_in[1];    // [2^19, 2] float32
    float2*       out = (float2*)d_out;            // [N, 16*2] float32

    int npts  = in_sizes[0] / 3;
    int total = npts * 16;
    int blocks = (total + 255) / 256;
    FeatureField_kernel<<<blocks, 256, 0, stream>>>(x, tab, out, total);
}